// Round 6
// baseline (108.718 us; speedup 1.0000x reference)
//
#include <hip/hip_runtime.h>
#include <stdint.h>
#include <stddef.h>

#define IDIM 256

typedef __attribute__((ext_vector_type(8))) short bf16x8;
typedef __attribute__((ext_vector_type(4))) float f32x4;

__device__ __forceinline__ short f2bf(float f) {
    union { float f; unsigned u; } v; v.f = f;
    unsigned r = v.u + 0x7FFFu + ((v.u >> 16) & 1u);
    return (short)(r >> 16);
}

// LDS map: [0,73728) packed M tiles (72 x 1KB), [73728,74752) FI,
//          [74752,78848) FW, [78848,95232) Kb fragment tiles (16 x 1KB).
#define FIOFF 73728
#define FWOFF 74752
#define KOFF  78848
#define LDSZ  95232

// Packed-tile base: active tiles (ti 16-rows, tj 32-cols), ti <= 2*tj+1.
// base = (tj^2+tj+ti)*1024. Tile rows are 64 B; swizzle stays within the row:
// SWZ(r) = XOR of byte-offset bits 4,5 only (2-way banking = free, m136).
#define SWZ(r) ((((r) >> 1) & 3) << 4)

__global__ __launch_bounds__(1024, 4)
void fused_qform(const float* __restrict__ X, const float* __restrict__ K,
                 const float* __restrict__ FW, const int* __restrict__ FI,
                 float* __restrict__ out) {
    __shared__ char lds[LDSZ];
    const int tid  = threadIdx.x;
    const int lane = tid & 63;
    const int wave = tid >> 6;           // 0..15
    const int l15  = lane & 15;
    const int g    = lane >> 4;          // 0..3
    const int wrow = blockIdx.x * 256 + wave * 16;
    const int kbase = g * 8;

    // ======== region A: issue ALL prologue global loads (K, FW, FI) ========
    // These must be OLDEST in the vmcnt queue so the pre-barrier wait can
    // retire them with vmcnt(8) while the X ring stays in flight (in-order
    // retirement: K before X in issue order is what makes this possible).
    float kv[8];
    {
        const float* kr = K + (size_t)(16 * wave + l15) * 30 + kbase;
        #pragma unroll
        for (int e = 0; e < 8; ++e)
            kv[e] = (kbase + e < 30) ? kr[e] : 0.f;   // guarded: 8 dword loads
    }
    if (wave < 4) {
        const char* src = (const char*)FW + wave * 1024 + lane * 16;
        __builtin_amdgcn_global_load_lds(
            (const __attribute__((address_space(1))) unsigned*)src,
            (__attribute__((address_space(3))) unsigned*)(lds + FWOFF + wave * 1024),
            16, 0, 0);
    } else if (wave == 4) {
        const char* src = (const char*)FI + lane * 16;
        __builtin_amdgcn_global_load_lds(
            (const __attribute__((address_space(1))) unsigned*)src,
            (__attribute__((address_space(3))) unsigned*)(lds + FIOFF),
            16, 0, 0);
    }
    __builtin_amdgcn_sched_barrier(0);

    // ======== region B: issue X ring chunks 0..3 (stream starts at t=0) ====
    const float* xrow = X + (size_t)(wrow + l15) * IDIM + kbase;
    float4 pa[4], pb[4];               // ring-of-4 X prefetch (32 VGPR)
    pa[0] = *(const float4*)(xrow + 0 * 32);
    pb[0] = *(const float4*)(xrow + 0 * 32 + 4);
    pa[1] = *(const float4*)(xrow + 1 * 32);
    pb[1] = *(const float4*)(xrow + 1 * 32 + 4);
    pa[2] = *(const float4*)(xrow + 2 * 32);
    pb[2] = *(const float4*)(xrow + 2 * 32 + 4);
    pa[3] = *(const float4*)(xrow + 3 * 32);
    pb[3] = *(const float4*)(xrow + 3 * 32 + 4);
    __builtin_amdgcn_sched_barrier(0);

    // ======== region C: cvt K -> Kb LDS tiles, zero-fill, counted barrier ==
    // Kb tile t, lane l holds K[16t + l15][g*8+e] as bf16 at
    // lds[KOFF + t*1024 + l*16] — exactly the 16x16x32 A/B fragment bytes.
    {
        bf16x8 f;
        #pragma unroll
        for (int e = 0; e < 8; ++e) f[e] = f2bf(kv[e]);
        *(bf16x8*)(lds + KOFF + wave * 1024 + lane * 16) = f;
    }
    // zero the 8 strictly-lower half-tiles (ti=2tj+1, low j-half): 1024 x 4B
    {
        const int ht = tid >> 7;               // 0..7
        const int r  = (tid >> 3) & 15;        // row
        const int a  = tid & 7;                // 4B slot in low half
        const int zb = ((ht * (ht + 1) + (2 * ht + 1)) << 10) + r * 64 + ((a * 4) ^ SWZ(r));
        *(unsigned*)(lds + zb) = 0u;
    }
    // barrier 1: retire K (8) + FW/FI (1) — the 8 X loads STAY IN FLIGHT.
    asm volatile("s_waitcnt vmcnt(8) lgkmcnt(0)" ::: "memory");
    __builtin_amdgcn_s_barrier();
    asm volatile("" ::: "memory");

    // ================= build phase (zero VMEM; frags via ds_read) ===========
    {
        const f32x4 kz = (f32x4){0.f, 0.f, 0.f, 0.f};
        const int* ldsFI = (const int*)(lds + FIOFF);
        const float* ldsFW = (const float*)(lds + FWOFF);

        const int v   = wave >> 1;     // column pair (v, 15-v)
        const int par = wave & 1;      // even/odd ta split within the pair
        const int tb1 = v;
        const int tb2 = 15 - v;
        const bf16x8 bf1 = *(const bf16x8*)(lds + KOFF + tb1 * 1024 + lane * 16);
        const bf16x8 bf2 = *(const bf16x8*)(lds + KOFF + tb2 * 1024 + lane * 16);
        const int fij1 = ldsFI[16 * tb1 + l15];
        const int fij2 = ldsFI[16 * tb2 + l15];

        // Build tile (ta,tb): kk = Afrag(ta) x Bfrag(tb), D[row=g*4+q][col=l15].
        // M[i][j] = (j>i) ? kk*FW[FI[i]][FI[j]] : 0, bf16 into packed tile:
        // physical = base + i15*64 + (((tb&1)*32 + 2*l15) ^ SWZ(i15))
#define BUILD_TILE(ta, tb, fb, fij) do {                                          \
        const bf16x8 aa = *(const bf16x8*)(lds + KOFF + (ta) * 1024 + lane * 16); \
        f32x4 kk = __builtin_amdgcn_mfma_f32_16x16x32_bf16(aa, fb, kz, 0, 0, 0);  \
        const int tjm = (tb) >> 1;                                                \
        const int mb  = ((tjm * (tjm + 1) + (ta)) << 10);                         \
        const int jb0 = (((tb) & 1) << 5) + 2 * l15;                              \
        const int j   = 16 * (tb) + l15;                                          \
        _Pragma("unroll")                                                         \
        for (int q = 0; q < 4; ++q) {                                             \
            const int i15 = g * 4 + q;                                            \
            const int i   = 16 * (ta) + i15;                                      \
            const float fw = ldsFW[ldsFI[16 * (ta) + i15] * 32 + (fij)];          \
            const float val = (j > i) ? kk[q] * fw : 0.f;                         \
            *(short*)(lds + mb + i15 * 64 + (jb0 ^ SWZ(i15))) = f2bf(val);        \
        }                                                                         \
    } while (0)

        #pragma unroll
        for (int ta = 0; ta < 16; ++ta) {
            if ((ta & 1) == par) {
                if (ta <= tb1) BUILD_TILE(ta, tb1, bf1, fij1);
                if (ta <= tb2) BUILD_TILE(ta, tb2, bf2, fij2);
            }
        }
#undef BUILD_TILE
    }
    // ================= end build phase =================

    // barrier 2: M visible. NO vmcnt drain — X chunks stay in flight.
    asm volatile("s_waitcnt lgkmcnt(0)" ::: "memory");
    __builtin_amdgcn_s_barrier();
    asm volatile("" ::: "memory");

    // ---- main loop: tj-outer, ring-of-4 prefetch, acc[16] ----
    f32x4 acc[16];
    #pragma unroll
    for (int t = 0; t < 16; ++t) acc[t] = (f32x4){0.f, 0.f, 0.f, 0.f};

    const unsigned laneoff = (unsigned)l15 * 64u + (unsigned)((g * 16) ^ SWZ(l15));

    #pragma unroll
    for (int tj = 0; tj < 8; ++tj) {
        const int s = tj & 3;                      // compile-time after unroll
        const float4 fa = pa[s], fb = pb[s];
        bf16x8 af;
        af[0] = f2bf(fa.x); af[1] = f2bf(fa.y); af[2] = f2bf(fa.z); af[3] = f2bf(fa.w);
        af[4] = f2bf(fb.x); af[5] = f2bf(fb.y); af[6] = f2bf(fb.z); af[7] = f2bf(fb.w);
        if (tj < 4) {                              // re-issue this slot for chunk tj+4
            pa[s] = *(const float4*)(xrow + (tj + 4) * 32);
            pb[s] = *(const float4*)(xrow + (tj + 4) * 32 + 4);
        }
        #pragma unroll
        for (int ti = 0; ti < 16; ++ti) {
            if (ti <= 2 * tj + 1) {
                const bf16x8 b = *(const bf16x8*)(lds + ((tj * (tj + 1) + ti) << 10) + laneoff);
                acc[ti] = __builtin_amdgcn_mfma_f32_16x16x32_bf16(af, b, acc[ti], 0, 0, 0);
            }
        }
    }

    // ---- fold: out[m] = sum_n X[m][n] * Y[m][n]  (X re-read, L2/L3-hot) ----
    float psum[4] = {0.f, 0.f, 0.f, 0.f};
    const float* xm = X + (size_t)(wrow + g * 4) * IDIM + l15;
    #pragma unroll
    for (int ti = 0; ti < 16; ++ti) {
        #pragma unroll
        for (int q = 0; q < 4; ++q)
            psum[q] += xm[(size_t)q * IDIM + ti * 16] * acc[ti][q];
    }

    #pragma unroll
    for (int q = 0; q < 4; ++q) {
        float v = psum[q];
        v += __shfl_xor(v, 1, 64);
        v += __shfl_xor(v, 2, 64);
        v += __shfl_xor(v, 4, 64);
        v += __shfl_xor(v, 8, 64);
        psum[q] = v;
    }
    if (l15 == 0) {
        #pragma unroll
        for (int q = 0; q < 4; ++q)
            out[wrow + g * 4 + q] = psum[q];
    }
}

extern "C" void kernel_launch(void* const* d_in, const int* in_sizes, int n_in,
                              void* d_out, int out_size, void* d_ws, size_t ws_size,
                              hipStream_t stream) {
    const float* X  = (const float*)d_in[0];   // (65536, 256) f32
    const float* K  = (const float*)d_in[1];   // (256, 30)  f32
    const float* FW = (const float*)d_in[2];   // (32, 32)   f32
    const int*   FI = (const int*)d_in[3];     // (256,)     i32
    const int batch = in_sizes[0] / IDIM;      // 65536
    fused_qform<<<dim3(batch / 256), dim3(1024), 0, stream>>>(X, K, FW, FI, (float*)d_out);
}